// Round 12
// baseline (14.666 us; speedup 1.0000x reference)
//
#include <hip/hip_runtime.h>

// Problem constants (fixed by the reference).
#define BSZ    16      // batch
#define NN     1024    // tokens per batch
#define DIN    512     // input dim
#define KD     256     // NUM_CAPS * DIM_CAPS
#define NCAPS  16
#define EPS    1e-7f

#define NSPLIT  16                   // column splits (32 cols each)
#define ICHUNK  (DIN / NSPLIT)       // 32
#define NHALF   4                    // row quarters (256 rows each)
#define NPART   (NSPLIT * NHALF)     // 64 partials per (b,d)
#define ROWS    (NN / NHALF)         // 256 rows per block

// ---------------------------------------------------------------------------
// Fused A+B (R11 structure, occupancy x2): grid = BSZ*NPART = 1024 blocks
// (b, s, quarter) x 256 threads = 4 blocks/CU, 16 waves/CU (R11 had 2/CU).
// No cross-block handoff (ledger: fences +45us, in-graph memset ~10us,
// atomic publish +1-3us, coop grid.sync = same wbl2 mechanism as fences).
//
// Block (b,s,q): col-sums input[b][q*256 .. +256)[32s .. 32s+32) directly
// (row segment = 128 B = one aligned cache line, zero over-fetch), reduces
// via LDS to xs[32], dots with the LDS-staged 32 KB W chunk:
//   P2[b][s*4+q][d] = sum_i xs[i] * W[32s+i][d]
// Exact-degeneracy math (validated R1-R11): out = squash(H/16), H = colsum@W.
// ---------------------------------------------------------------------------
__global__ __launch_bounds__(256, 4) void colsum_gemm(
    const float* __restrict__ in, const float* __restrict__ W,
    float* __restrict__ P2)
{
    __shared__ float  wl[ICHUNK][KD];    // 32 KB   W chunk
    __shared__ float4 shp[32][8];        //  4 KB   per-rowgroup col partials
    __shared__ float4 pr[8][8];          //  1 KB
    __shared__ float  xs[ICHUNK];        // 128 B   (37.1 KB total, 4/CU ok)

    const int blk = blockIdx.x;
    const int b   = blk >> 6;            // / NPART
    const int r5  = blk & (NPART - 1);   // s*NHALF + q
    const int s   = r5 >> 2;
    const int q   = r5 & 3;
    const int t   = threadIdx.x;

    // ---- Stage W chunk: 8 independent float4 loads (issued first).
    const float4* W4 = (const float4*)W + (size_t)(s * ICHUNK) * (KD / 4);
    float4 wv[8];
    #pragma unroll
    for (int k = 0; k < 8; ++k)
        wv[k] = W4[k * 256 + t];         // 2048 float4 = 32 rows x 64

    // ---- Col-sum 256 rows x 32 cols. Thread (rg = t>>3, c4 = t&7):
    // 8 independent float4 loads at row stride 32.
    {
        const int rg = t >> 3;           // 0..31
        const int c4 = t & 7;            // float4 col within chunk
        const float4* base = (const float4*)in
            + ((size_t)(b * NN + q * ROWS) * (DIN / 4))
            + (size_t)s * (ICHUNK / 4) + c4;
        float4 a = make_float4(0.f, 0.f, 0.f, 0.f);
        #pragma unroll
        for (int j = 0; j < ROWS / 32; ++j) {   // 8
            float4 v = base[(size_t)(rg + 32 * j) * (DIN / 4)];
            a.x += v.x; a.y += v.y; a.z += v.z; a.w += v.w;
        }
        shp[rg][c4] = a;
    }

    // ---- LDS-write W chunk (waits the W loads; one round).
    #pragma unroll
    for (int k = 0; k < 8; ++k) {
        int idx  = k * 256 + t;
        int row  = idx >> 6;             // 0..31
        int col4 = idx & 63;
        *(float4*)&wl[row][col4 * 4] = wv[k];
    }
    __syncthreads();

    // ---- Reduce 32 rowgroups -> xs[32] (fixed order: 4-tree then 8).
    if (t < 64) {
        const int rg2 = t >> 3;          // 0..7
        const int c4  = t & 7;
        float4 a = shp[rg2 * 4 + 0][c4];
        #pragma unroll
        for (int u = 1; u < 4; ++u) {
            float4 v = shp[rg2 * 4 + u][c4];
            a.x += v.x; a.y += v.y; a.z += v.z; a.w += v.w;
        }
        pr[rg2][c4] = a;
    }
    __syncthreads();
    if (t < 8) {
        float4 a = pr[0][t];
        #pragma unroll
        for (int u = 1; u < 8; ++u) {
            float4 v = pr[u][t];
            a.x += v.x; a.y += v.y; a.z += v.z; a.w += v.w;
        }
        *(float4*)&xs[t * 4] = a;
    }
    __syncthreads();

    // ---- 32-deep dot entirely from LDS; write partial.
    float acc = 0.f;
    #pragma unroll
    for (int i = 0; i < ICHUNK; ++i)
        acc += xs[i] * wl[i][t];
    P2[((size_t)b * NPART + r5) * KD + t] = acc;
}

// ---------------------------------------------------------------------------
// Kernel C: reduce NPART=64 partials, squash, write 16 identical k-copies.
// grid = 16 blocks x 256 threads; 64 KB P2 tile staged in ONE float4 round
// (16 independent loads/thread), fixed-order reduce => deterministic.
// ---------------------------------------------------------------------------
__global__ __launch_bounds__(256) void squash_out(
    const float* __restrict__ P2, float* __restrict__ out)
{
    __shared__ float part[4][KD];
    __shared__ float svs[KD];
    __shared__ float red[KD];

    const int b = blockIdx.x;
    const int t = threadIdx.x;
    const int g  = t >> 6;                     // 0..3 (16 rows each)
    const int d4 = t & 63;                     // float4 col 0..63

    const float4* P24 = (const float4*)P2 + (size_t)b * NPART * (KD / 4);
    float4 a = make_float4(0.f, 0.f, 0.f, 0.f);
    #pragma unroll
    for (int j = 0; j < 16; ++j) {             // 16 independent loads
        float4 v = P24[(size_t)(g * 16 + j) * (KD / 4) + d4];
        a.x += v.x; a.y += v.y; a.z += v.z; a.w += v.w;
    }
    *(float4*)&part[g][d4 * 4] = a;
    __syncthreads();

    const float sv = (part[0][t] + part[1][t] + part[2][t] + part[3][t])
                     * (1.0f / 16.0f);         // softmax c = 1/16 exactly
    svs[t] = sv;
    red[t] = sv * sv;
    __syncthreads();
    for (int off = 128; off > 0; off >>= 1) {
        if (t < off) red[t] += red[t + off];
        __syncthreads();
    }
    const float sq    = red[0];
    const float scale = (sq / (1.0f + sq)) / sqrtf(sq + EPS);
    const float o     = scale * svs[t];

    #pragma unroll
    for (int k = 0; k < NCAPS; ++k)
        out[((size_t)b * NCAPS + k) * KD + t] = o;
}

extern "C" void kernel_launch(void* const* d_in, const int* in_sizes, int n_in,
                              void* d_out, int out_size, void* d_ws, size_t ws_size,
                              hipStream_t stream)
{
    const float* in = (const float*)d_in[0];  // [16,1024,512] f32
    const float* W  = (const float*)d_in[1];  // [512,256] f32
    float* out = (float*)d_out;               // [16,16,256] f32

    float* P2 = (float*)d_ws;                 // 16*64*256 f32 = 1 MB

    colsum_gemm<<<BSZ * NPART, 256, 0, stream>>>(in, W, P2);
    squash_out<<<BSZ, 256, 0, stream>>>(P2, out);
}

// Round 13
// 12.678 us; speedup vs baseline: 1.1569x; 1.1569x over previous
//
#include <hip/hip_runtime.h>

// Problem constants (fixed by the reference).
#define BSZ    16      // batch
#define NN     1024    // tokens per batch
#define DIN    512     // input dim
#define KD     256     // NUM_CAPS * DIM_CAPS
#define NCAPS  16
#define EPS    1e-7f

#define NSPLIT  16                   // column splits (32 cols each)
#define ICHUNK  (DIN / NSPLIT)       // 32
#define NHALF   2                    // row halves (512 rows each)
#define NPART   (NSPLIT * NHALF)     // 32 partials per (b,d)

// ---------------------------------------------------------------------------
// PROVEN best (R11: 12.96 us, absmax 4.8e-7). Reverted from R12's NHALF=4
// (14.67: doubled W-staging L2 traffic + doubled per-block fixed costs;
// input stream was already BW-saturated at 2 blocks/CU).
//
// Structure ledger (13 rounds): 2-node-no-handoff 12.96 < 3-node 15.10 <
// 2-node+atomics 16.26 < 16-block-tail shapes ~19 < memset-node 32.5 <
// fence-storm 60.7. Kernel-boundary coherence is the cheapest grid sync;
// every in-kernel handoff (fence/atomic/memset, coop wbl2) costs more.
//
// Math (validated R1-R12, absmax <= 1.5e-5): routing is exactly degenerate
// (input_hat independent of k) => softmax stays exactly 1/16, agreement
// update is k-constant => out[b,k,:] = squash((1/16)*(sum_n in[b,n,:])@W).
// ---------------------------------------------------------------------------

// Fused A+B: grid = 512 blocks (b, s, half) x 256 threads (2 blocks/CU,
// 8 waves/CU -- the proven streaming shape). Block (b,s,half): col-sums
// input[b][half*512 .. +512)[32s .. 32s+32) directly (row segment = 128 B =
// one aligned cache line, zero over-fetch, float4 16 B/lane), reduces via
// LDS to xs[32], dots with the LDS-staged 32 KB W chunk:
//   P2[b][s*2+half][d] = sum_i xs[i] * W[32s+i][d]
__global__ __launch_bounds__(256, 2) void colsum_gemm(
    const float* __restrict__ in, const float* __restrict__ W,
    float* __restrict__ P2)
{
    __shared__ float  wl[ICHUNK][KD];    // 32 KB   W chunk
    __shared__ float4 shp[32][8];        //  4 KB   per-rowgroup col partials
    __shared__ float4 pr[8][8];          //  1 KB
    __shared__ float  xs[ICHUNK];        // 128 B

    const int blk  = blockIdx.x;
    const int b    = blk >> 5;           // batch
    const int r5   = blk & 31;           // s*2 + half
    const int s    = r5 >> 1;
    const int half = r5 & 1;
    const int t    = threadIdx.x;

    // ---- Stage W chunk: 8 independent float4 loads (issued first).
    const float4* W4 = (const float4*)W + (size_t)(s * ICHUNK) * (KD / 4);
    float4 wv[8];
    #pragma unroll
    for (int k = 0; k < 8; ++k)
        wv[k] = W4[k * 256 + t];         // 2048 float4 = 32 rows x 64

    // ---- Col-sum 512 rows x 32 cols. Thread (rg = t>>3, c4 = t&7):
    // 16 independent float4 loads at row stride 32.
    {
        const int rg = t >> 3;           // 0..31
        const int c4 = t & 7;            // float4 col within chunk
        const float4* base = (const float4*)in
            + ((size_t)(b * NN + half * 512) * (DIN / 4))
            + (size_t)s * (ICHUNK / 4) + c4;
        float4 a = make_float4(0.f, 0.f, 0.f, 0.f);
        #pragma unroll
        for (int j = 0; j < 16; ++j) {
            float4 v = base[(size_t)(rg + 32 * j) * (DIN / 4)];
            a.x += v.x; a.y += v.y; a.z += v.z; a.w += v.w;
        }
        shp[rg][c4] = a;
    }

    // ---- LDS-write W chunk (waits the W loads; one round).
    #pragma unroll
    for (int k = 0; k < 8; ++k) {
        int idx  = k * 256 + t;
        int row  = idx >> 6;             // 0..31
        int col4 = idx & 63;
        *(float4*)&wl[row][col4 * 4] = wv[k];
    }
    __syncthreads();

    // ---- Reduce 32 rowgroups -> xs[32] (fixed order: 4-tree then 8).
    if (t < 64) {
        const int rg2 = t >> 3;          // 0..7
        const int c4  = t & 7;
        float4 a = shp[rg2 * 4 + 0][c4];
        #pragma unroll
        for (int u = 1; u < 4; ++u) {
            float4 v = shp[rg2 * 4 + u][c4];
            a.x += v.x; a.y += v.y; a.z += v.z; a.w += v.w;
        }
        pr[rg2][c4] = a;
    }
    __syncthreads();
    if (t < 8) {
        float4 a = pr[0][t];
        #pragma unroll
        for (int u = 1; u < 8; ++u) {
            float4 v = pr[u][t];
            a.x += v.x; a.y += v.y; a.z += v.z; a.w += v.w;
        }
        *(float4*)&xs[t * 4] = a;
    }
    __syncthreads();

    // ---- 32-deep dot entirely from LDS; write partial.
    float acc = 0.f;
    #pragma unroll
    for (int i = 0; i < ICHUNK; ++i)
        acc += xs[i] * wl[i][t];
    P2[((size_t)b * NPART + r5) * KD + t] = acc;
}

// Kernel C: reduce NPART=32 partials, squash, write 16 identical k-copies.
// grid = 16 blocks x 256 threads; 32 KB P2 tile staged in ONE float4 round
// (8 independent loads/thread), fixed-order reduce => deterministic.
__global__ __launch_bounds__(256) void squash_out(
    const float* __restrict__ P2, float* __restrict__ out)
{
    __shared__ float part[4][KD];
    __shared__ float svs[KD];
    __shared__ float red[KD];

    const int b = blockIdx.x;
    const int t = threadIdx.x;
    const int g  = t >> 6;                     // 0..3 (8 rows each)
    const int d4 = t & 63;                     // float4 col 0..63

    const float4* P24 = (const float4*)P2 + (size_t)b * NPART * (KD / 4);
    float4 a = make_float4(0.f, 0.f, 0.f, 0.f);
    #pragma unroll
    for (int j = 0; j < 8; ++j) {              // 8 independent loads
        float4 v = P24[(size_t)(g * 8 + j) * (KD / 4) + d4];
        a.x += v.x; a.y += v.y; a.z += v.z; a.w += v.w;
    }
    *(float4*)&part[g][d4 * 4] = a;
    __syncthreads();

    const float sv = (part[0][t] + part[1][t] + part[2][t] + part[3][t])
                     * (1.0f / 16.0f);         // softmax c = 1/16 exactly
    svs[t] = sv;
    red[t] = sv * sv;
    __syncthreads();
    for (int off = 128; off > 0; off >>= 1) {
        if (t < off) red[t] += red[t + off];
        __syncthreads();
    }
    const float sq    = red[0];
    const float scale = (sq / (1.0f + sq)) / sqrtf(sq + EPS);
    const float o     = scale * svs[t];

    #pragma unroll
    for (int k = 0; k < NCAPS; ++k)
        out[((size_t)b * NCAPS + k) * KD + t] = o;
}

extern "C" void kernel_launch(void* const* d_in, const int* in_sizes, int n_in,
                              void* d_out, int out_size, void* d_ws, size_t ws_size,
                              hipStream_t stream)
{
    const float* in = (const float*)d_in[0];  // [16,1024,512] f32
    const float* W  = (const float*)d_in[1];  // [512,256] f32
    float* out = (float*)d_out;               // [16,16,256] f32

    float* P2 = (float*)d_ws;                 // 16*32*256 f32 = 512 KB

    colsum_gemm<<<BSZ * NPART, 256, 0, stream>>>(in, W, P2);
    squash_out<<<BSZ, 256, 0, stream>>>(P2, out);
}